// Round 5
// baseline (247.369 us; speedup 1.0000x reference)
//
#include <hip/hip_runtime.h>
#include <cstdint>
#include <cstddef>

// Problem constants
constexpr int NPTS = 65536;
constexpr int B    = 256;
constexpr int TPB  = 512;              // 8 waves/block
constexpr int CCAND = 1024;            // per-row candidate cap (mean 655, sigma 25.5 -> +14σ)

// Workspace layout (word offsets). Tiny now: barrier + maxes + sums + normals.
constexpr size_t WSO_BAR   = 0;        // 4 words (1 used)
constexpr size_t WSO_PMAXP = 4;        // 256 u32 (monotonic-encoded f32)
constexpr size_t WSO_PMAXN = 260;      // 256 u32
constexpr size_t WSO_ISUMP = 516;      // 256 f32 (inactive sums, +proj)
constexpr size_t WSO_ISUMN = 772;      // 256 f32
constexpr size_t WSO_INIT_WORDS = 1028;// memset region [0, 1028)
constexpr size_t WSO_NRM   = 1028;     // 256*8 f32 (byte off 4112, 16B-aligned)

__device__ __forceinline__ float clipp(float x) {
    return fminf(fmaxf(x, 1e-5f), 0.99999f);
}
__device__ __forceinline__ unsigned f2mono(float f) {
    unsigned u = __float_as_uint(f);
    return (u & 0x80000000u) ? ~u : (u | 0x80000000u);
}
__device__ __forceinline__ float mono2f(unsigned e) {
    return __uint_as_float((e & 0x80000000u) ? (e ^ 0x80000000u) : ~e);
}
__device__ __forceinline__ int cand_bin(float v) {
    int b = (int)((v - 0.99f) * 102400.0f);   // 1024 bins over [0.99, 1.0)
    return min(max(b, 0), 1023);
}
// fma order identical everywhere (P3/P4/P5) -> bitwise-identical projections.
__device__ __forceinline__ float dot8v(float4 a, float4 b, float4 n0, float4 n1) {
    float d = a.x * n0.x;
    d = fmaf(a.y, n0.y, d); d = fmaf(a.z, n0.z, d); d = fmaf(a.w, n0.w, d);
    d = fmaf(b.x, n1.x, d); d = fmaf(b.y, n1.y, d); d = fmaf(b.z, n1.z, d);
    d = fmaf(b.w, n1.w, d);
    return d;
}

// Device-scope grid barrier: one packed word, high16 = generation, low16 = count.
// Arrive order (read-gen-via-fetch-add) is race-free: an arrival's increment
// always lands in its own generation (gen can only bump after all arrivals).
// Guarded spin breaks a would-be hang into a visible failure.
__device__ __forceinline__ void gridbar(unsigned* bar, unsigned nblk) {
    __syncthreads();
    if (threadIdx.x == 0) {
        __threadfence();   // agent-scope release of all prior global writes
        unsigned old = __hip_atomic_fetch_add(bar, 1u, __ATOMIC_ACQ_REL,
                                              __HIP_MEMORY_SCOPE_AGENT);
        unsigned mygen = old >> 16;
        if ((old & 0xFFFFu) == nblk - 1u) {
            // last arriver: zero count, bump generation (single atomic)
            __hip_atomic_fetch_add(bar, (1u << 16) - nblk, __ATOMIC_ACQ_REL,
                                   __HIP_MEMORY_SCOPE_AGENT);
        } else {
            int guard = 0;
            while ((__hip_atomic_load(bar, __ATOMIC_ACQUIRE,
                                      __HIP_MEMORY_SCOPE_AGENT) >> 16) == mygen) {
                __builtin_amdgcn_s_sleep(32);
                if (++guard > (1 << 22)) break;   // hang-breaker
            }
        }
        __threadfence();   // acquire side
    }
    __syncthreads();
}

// ---------------------------------------------------------------------------
// ONE persistent kernel, 256 blocks x 512 threads (provably all co-resident:
// capacity is 4 blocks/CU, grid = #CUs).
//  P1 (block=row):  stream row's 64K probs, sum, collect >=0.99 cands in LDS
//  P2 (block=row):  exact top-128/top-64, moments, 64-lane tournament Jacobi
//  --- grid barrier ---
//  P3 (block=slice): thread=row over 256-point slice, atomicMax global maxes
//  --- grid barrier ---
//  P4 (block=slice): EXACT inactive-term accumulation (no near-list approx)
//  --- grid barrier ---
//  P5 (block=row):  active term from LDS top-64 + combine -> out[row]
__global__ __launch_bounds__(TPB) void kFused(
    const float* __restrict__ prob, const float* __restrict__ points,
    float* __restrict__ ws, float* __restrict__ out)
{
    __shared__ __align__(16) unsigned long long cand[CCAND]; // 8KB; P3+: nrm_all[256][8]
    __shared__ unsigned long long comp[256];                 // 2KB
    __shared__ int   hist[1024];                             // 4KB; P3+: maxf[1024]
    __shared__ float sw[128];
    __shared__ float pc[128][9];
    __shared__ float sred[44][4];
    __shared__ float slotm[44];
    __shared__ float wpart[2];
    __shared__ float covm[64];
    __shared__ float t64v[64];
    __shared__ int   t64i[64];
    __shared__ __align__(16) float nrm_s[8];
    __shared__ float wred8[8];
    __shared__ float plane_s, facet_s, anorm_s, sump_s;
    __shared__ int   lcnt, ccnt, bt_s;

    const int tid = threadIdx.x;
    const int row = blockIdx.x;
    float* nrm_all = (float*)cand;
    float* maxf    = (float*)hist;
    unsigned* bar  = (unsigned*)ws + WSO_BAR;

    hist[tid] = 0; hist[tid + 512] = 0;
    if (tid == 0) { lcnt = 0; ccnt = 0; bt_s = 0; }
    __syncthreads();

    // ---- P1: stream this row's probs (64 MB total across grid, read once) ----
    {
        const float4* p4 = (const float4*)(prob + (size_t)row * NPTS);
        float lsum = 0.f;
        #pragma unroll 1
        for (int g = 0; g < 4; g++) {
            float4 v[8];
            #pragma unroll
            for (int i = 0; i < 8; i++) v[i] = p4[(g * 8 + i) * TPB + tid];
            #pragma unroll
            for (int i = 0; i < 8; i++) {
                float c0 = clipp(v[i].x), c1 = clipp(v[i].y);
                float c2 = clipp(v[i].z), c3 = clipp(v[i].w);
                lsum += (c0 + c1) + (c2 + c3);
                float mx = fmaxf(fmaxf(c0, c1), fmaxf(c2, c3));
                if (mx >= 0.99f) {
                    int bi = ((g * 8 + i) * TPB + tid) * 4;
                    float c4[4] = {c0, c1, c2, c3};
                    #pragma unroll
                    for (int j = 0; j < 4; j++) {
                        if (c4[j] >= 0.99f) {
                            int p_ = atomicAdd(&lcnt, 1);
                            if (p_ < CCAND)
                                cand[p_] = (((unsigned long long)__float_as_uint(c4[j])) << 32)
                                         | (unsigned)~(bi + j);
                        }
                    }
                }
            }
        }
        #pragma unroll
        for (int off = 32; off; off >>= 1) lsum += __shfl_down(lsum, off);
        if ((tid & 63) == 0) wred8[tid >> 6] = lsum;
    }
    __syncthreads();
    if (tid == 0) {
        float s = 0.f;
        #pragma unroll
        for (int k = 0; k < 8; k++) s += wred8[k];
        sump_s = s;
    }
    __syncthreads();

    // ---- P2: exact top-128/top-64 + moments + Jacobi (verbatim kB math) ----
    const int mc = min(lcnt, CCAND);
    for (int i = tid; i < mc; i += TPB)
        atomicAdd(&hist[cand_bin(__uint_as_float((unsigned)(cand[i] >> 32)))], 1);
    __syncthreads();

    if (tid < 64) {   // threshold bin via one wave: suffix-scan 64x16 bins
        int h[16]; int g2 = 0;
        #pragma unroll
        for (int k = 0; k < 16; k++) { h[k] = hist[tid * 16 + k]; g2 += h[k]; }
        int s = g2;
        #pragma unroll
        for (int off = 1; off < 64; off <<= 1) {
            int o = __shfl_down(s, off);
            if (tid + off < 64) s += o;
        }
        int Snext = __shfl_down(s, 1);
        if (tid == 63) Snext = 0;
        if (s >= 128 && Snext < 128) {
            int acc = Snext, bt = tid * 16;
            #pragma unroll
            for (int k = 15; k >= 0; k--) {
                acc += h[k];
                if (acc >= 128) { bt = tid * 16 + k; break; }
            }
            bt_s = bt;
        }
    }
    __syncthreads();

    const int btv = bt_s;
    for (int i = tid; i < mc; i += TPB) {
        unsigned long long k = cand[i];
        if (cand_bin(__uint_as_float((unsigned)(k >> 32))) >= btv) {
            int p_ = atomicAdd(&ccnt, 1);
            if (p_ < 256) comp[p_] = k;
        }
    }
    __syncthreads();
    const int m = min(ccnt, 256);

    if (tid < 128) {
        sw[tid] = 0.f;
        #pragma unroll
        for (int j = 0; j < 9; j++) pc[tid][j] = (j == 8) ? 1.f : 0.f;
    }
    if (tid < 64) { t64v[tid] = 0.f; t64i[tid] = 0; }
    unsigned long long ki = (tid < m) ? comp[tid] : 0ull;
    int rank = 0;
    for (int j = 0; j < m; j++) rank += (comp[j] > ki) ? 1 : 0;
    __syncthreads();

    if (tid < m && rank < 128) {   // rank order == lax.top_k order (key tiebreak)
        float v = __uint_as_float((unsigned)(ki >> 32));
        unsigned idx = ~(unsigned)(ki & 0xFFFFFFFFu);
        sw[rank] = v;
        const float4* pt = (const float4*)(points + (size_t)idx * 8);
        float4 q0 = pt[0], q1 = pt[1];
        pc[rank][0] = q0.x; pc[rank][1] = q0.y; pc[rank][2] = q0.z; pc[rank][3] = q0.w;
        pc[rank][4] = q1.x; pc[rank][5] = q1.y; pc[rank][6] = q1.z; pc[rank][7] = q1.w;
        if (rank < 64) { t64v[rank] = v; t64i[rank] = (int)idx; }
    }
    __syncthreads();

    if (tid < 128) {
        float ww = sw[tid];
        #pragma unroll
        for (int off = 32; off; off >>= 1) ww += __shfl_down(ww, off);
        if ((tid & 63) == 0) wpart[tid >> 6] = ww;
    }
    if (tid < 176) {   // moments: 44 slots x 4 partials
        int s = tid >> 2, part = tid & 3;
        int i_, j_;
        if (s < 36) {
            int rem = s; i_ = 0;
            while (rem >= 8 - i_) { rem -= 8 - i_; i_++; }
            j_ = i_ + rem;
        } else { i_ = s - 36; j_ = 8; }
        float acc = 0.f;
        for (int k = part * 32; k < part * 32 + 32; k++)
            acc += sw[k] * pc[k][i_] * pc[k][j_];
        sred[s][part] = acc;
    }
    __syncthreads();
    if (tid < 44) slotm[tid] = (sred[tid][0] + sred[tid][1]) + (sred[tid][2] + sred[tid][3]);
    __syncthreads();

    if (tid < 64) {
        float w128 = fmaxf(wpart[0] + wpart[1], 1e-6f);
        int i_ = tid >> 3, j_ = tid & 7;
        int a_ = min(i_, j_), b_ = max(i_, j_);
        int s3 = 8 * a_ - (a_ * (a_ - 1)) / 2 + (b_ - a_);
        covm[tid] = slotm[s3] / w128 - (slotm[36 + i_] / w128) * (slotm[36 + j_] / w128);
    }
    if (tid == 64) anorm_s = fmaxf(wpart[0], 1e-6f);
    __syncthreads();

    if (tid < 64) {   // element-parallel tournament Jacobi (verbatim)
        const int i = tid >> 3, j = tid & 7;
        float a = covm[tid];
        float v = (i == j) ? 1.f : 0.f;
        const unsigned PR[7] = {023456701u, 001234567u, 050712346u, 034067125u,
                                012305674u, 067120453u, 045671032u};
        #pragma unroll 1
        for (int sweep = 0; sweep < 6; sweep++) {
            #pragma unroll
            for (int r = 0; r < 7; r++) {
                const unsigned pk = PR[r];
                const int rp = (pk >> (3 * i)) & 7;
                const int cp = (pk >> (3 * j)) & 7;
                const int pr = min(i, rp), qr = max(i, rp);
                float app = __shfl(a, pr * 9);
                float aqq = __shfl(a, qr * 9);
                float apq = __shfl(a, pr * 8 + qr);
                float tau = 0.5f * (aqq - app);
                float den = fabsf(tau) + sqrtf(fmaf(tau, tau, apq * apq));
                float t = __fdividef(apq, den + 1e-38f);
                t = (tau < 0.f) ? -t : t;
                float cr = rsqrtf(fmaf(t, t, 1.f));
                float sr = t * cr;
                float cc = __shfl(cr, j * 9);
                float sc = __shfl(sr, j * 9);
                float oth = __shfl(a, rp * 8 + j);
                a = fmaf((i < rp) ? -sr : sr, oth, cr * a);
                float oth2 = __shfl(a, i * 8 + cp);
                a = fmaf((j < cp) ? -sc : sc, oth2, cc * a);
                float ov = __shfl(v, i * 8 + cp);
                v = fmaf((j < cp) ? -sc : sc, ov, cc * v);
            }
        }
        float dd[8];
        #pragma unroll
        for (int k = 0; k < 8; k++) dd[k] = __shfl(a, k * 9);
        float e0 = dd[0]; int i0 = 0;
        #pragma unroll
        for (int k = 1; k < 8; k++) if (dd[k] < e0) { e0 = dd[k]; i0 = k; }
        float e1 = 3.4e38f;
        #pragma unroll
        for (int k = 0; k < 8; k++) if (k != i0 && dd[k] < e1) e1 = dd[k];
        if (tid == 0) { plane_s = e0; facet_s = e0 / (e1 + 1e-6f); }
        if (j == i0) { nrm_s[i] = v; ws[WSO_NRM + (size_t)row * 8 + i] = v; }
    }

    gridbar(bar, gridDim.x);   // NRM complete everywhere

    // ---- P3: global projection maxes (thread=row over this block's slice) ----
    ((float4*)nrm_all)[tid] = ((const float4*)(ws + WSO_NRM))[tid];  // stage 256 normals
    __syncthreads();
    const int rt = tid & 255, sub = tid >> 8;
    const float4 n0 = ((float4*)nrm_all)[rt * 2], n1 = ((float4*)nrm_all)[rt * 2 + 1];
    const float4* pq = (const float4*)points
                     + ((size_t)blockIdx.x * 256 + (size_t)sub * 128) * 2;
    {
        float mp = -3.4e38f, mn = -3.4e38f;
        #pragma unroll 8
        for (int i = 0; i < 128; i++) {
            float4 a = pq[2 * i], b = pq[2 * i + 1];   // wave-uniform loads
            float d = dot8v(a, b, n0, n1);
            mp = fmaxf(mp, d);
            mn = fmaxf(mn, -d);
        }
        maxf[tid] = mp; maxf[512 + tid] = mn;
    }
    __syncthreads();
    if (tid < 256) {
        float mpf = fmaxf(maxf[tid], maxf[tid + 256]);
        float mnf = fmaxf(maxf[512 + tid], maxf[512 + tid + 256]);
        unsigned* wsu = (unsigned*)ws;
        atomicMax(&wsu[WSO_PMAXP + tid], f2mono(mpf));
        atomicMax(&wsu[WSO_PMAXN + tid], f2mono(mnf));
    }

    gridbar(bar, gridDim.x);   // maxes final

    // ---- P4: EXACT inactive accumulation (all points with 0.05+sb > 0) ----
    if (tid < 256) {
        unsigned* wsu = (unsigned*)ws;
        maxf[tid] = mono2f(__hip_atomic_load(&wsu[WSO_PMAXP + tid],
                            __ATOMIC_ACQUIRE, __HIP_MEMORY_SCOPE_AGENT));
        maxf[256 + tid] = mono2f(__hip_atomic_load(&wsu[WSO_PMAXN + tid],
                            __ATOMIC_ACQUIRE, __HIP_MEMORY_SCOPE_AGENT));
    }
    __syncthreads();
    {
        const float pvp = maxf[rt], pvn = maxf[256 + rt];
        const int gbase = blockIdx.x * 256 + sub * 128;
        float accp = 0.f, accn = 0.f;
        #pragma unroll 4
        for (int i = 0; i < 128; i++) {
            float4 a = pq[2 * i], b = pq[2 * i + 1];
            float d = dot8v(a, b, n0, n1);
            float tp = 0.05f + (d - pvp);
            float tn = 0.05f + (-d - pvn);
            if (tp > 0.f || tn > 0.f) {
                float w2 = 1.0f - clipp(prob[(size_t)rt * NPTS + (gbase + i)]);
                if (tp > 0.f) accp = fmaf(w2 * tp, tp, accp);
                if (tn > 0.f) accn = fmaf(w2 * tn, tn, accn);
            }
        }
        if (accp != 0.f) atomicAdd(ws + WSO_ISUMP + rt, accp);
        if (accn != 0.f) atomicAdd(ws + WSO_ISUMN + rt, accn);
    }

    gridbar(bar, gridDim.x);   // inactive sums final

    // ---- P5: active term (LDS top-64) + combine (block = row) ----
    if (tid < 64) {
        unsigned* wsu = (unsigned*)ws;
        float pmaxp = mono2f(__hip_atomic_load(&wsu[WSO_PMAXP + row],
                              __ATOMIC_ACQUIRE, __HIP_MEMORY_SCOPE_AGENT));
        float pmaxn = mono2f(__hip_atomic_load(&wsu[WSO_PMAXN + row],
                              __ATOMIC_ACQUIRE, __HIP_MEMORY_SCOPE_AGENT));
        float4 m0 = *(const float4*)&nrm_s[0];
        float4 m1 = *(const float4*)&nrm_s[4];
        float w   = t64v[tid];
        int   idx = t64i[tid];
        const float4* pt = (const float4*)(points + (size_t)idx * 8);
        float4 q0 = pt[0], q1 = pt[1];
        float d = dot8v(q0, q1, m0, m1);
        float sp = d - pmaxp, sn = -d - pmaxn;
        float ap = w * sp * sp;
        float an = w * sn * sn;
        #pragma unroll
        for (int off = 32; off; off >>= 1) {
            ap += __shfl_down(ap, off);
            an += __shfl_down(an, off);
        }
        if (tid == 0) {
            float ip  = __hip_atomic_load(ws + WSO_ISUMP + row,
                          __ATOMIC_ACQUIRE, __HIP_MEMORY_SCOPE_AGENT);
            float in_ = __hip_atomic_load(ws + WSO_ISUMN + row,
                          __ATOMIC_ACQUIRE, __HIP_MEMORY_SCOPE_AGENT);
            float inorm = fmaxf((float)NPTS - sump_s, 1e-6f);
            float bp = (ap / anorm_s) + 0.35f * (ip / inorm);
            float bn = (an / anorm_s) + 0.35f * (in_ / inorm);
            float bd = (bp <= bn) ? bp : bn;
            float def = fmaxf(26.0f - sump_s, 0.f);
            out[row] = plane_s + 8.0f * facet_s + 4.0f * bd + 25.0f * def * def;
        }
    }
}

// ---------------------------------------------------------------------------
extern "C" void kernel_launch(void* const* d_in, const int* in_sizes, int n_in,
                              void* d_out, int out_size, void* d_ws, size_t ws_size,
                              hipStream_t stream) {
    const float* prob   = (const float*)d_in[0];  // (256, 65536) f32
    const float* points = (const float*)d_in[1];  // (65536, 8) f32
    float* out = (float*)d_out;                   // (256,) f32
    float* ws  = (float*)d_ws;                    // ~12.3 KB used

    hipMemsetAsync(ws, 0, WSO_INIT_WORDS * sizeof(float), stream);  // bar+max+isum
    kFused<<<B, TPB, 0, stream>>>(prob, points, ws, out);
}

// Round 6
// 142.090 us; speedup vs baseline: 1.7409x; 1.7409x over previous
//
#include <hip/hip_runtime.h>
#include <cstdint>
#include <cstddef>

// Problem constants
constexpr int NPTS   = 65536;
constexpr int B      = 256;
constexpr int CHUNKS = 8;              // chunks per row (stream phase)
constexpr int CHUNK  = NPTS / CHUNKS;  // 8192 elements
constexpr int CCAP   = 160;            // per-chunk cap (mean 82, sigma 9 -> +8.7 sigma, P~2e-18)
constexpr int NBLK   = B * CHUNKS;     // 2048 stream blocks
constexpr int NEARCAP = 256;           // near-max list cap per row-sign

// Workspace layout (word offsets; u64 regions first => 8-byte aligned)
// Total 958,464 words = 3.66 MiB.
constexpr size_t WSO_CBUF    = 0;                                      // NBLK*CCAP u64
constexpr size_t WSO_NEAR    = WSO_CBUF + (size_t)NBLK * CCAP * 2;     // 2*B*NEARCAP u64
constexpr size_t WSO_NEARCNT = WSO_NEAR + (size_t)2 * B * NEARCAP * 2; // 2*B ints
constexpr size_t WSO_PSUM    = WSO_NEARCNT + 2 * B;                    // NBLK floats
constexpr size_t WSO_CCNT    = WSO_PSUM + NBLK;                        // NBLK ints
constexpr size_t WSO_PLANE   = WSO_CCNT + NBLK;                        // B floats
constexpr size_t WSO_FACET   = WSO_PLANE + B;                          // B floats
constexpr size_t WSO_NRM     = WSO_FACET + B;                          // B*8 floats (16B-aligned)
constexpr size_t WSO_SUMP    = WSO_NRM + (size_t)B * 8;                // B floats
constexpr size_t WSO_ANORM   = WSO_SUMP + B;                           // B floats
constexpr size_t WSO_T64V    = WSO_ANORM + B;                          // B*64 floats
constexpr size_t WSO_T64I    = WSO_T64V + (size_t)B * 64;              // B*64 ints
constexpr size_t WSO_PMAXP   = WSO_T64I + (size_t)B * 64;              // B uints
constexpr size_t WSO_PMAXN   = WSO_PMAXP + B;                          // B uints

__device__ __forceinline__ float clipp(float x) {
    return fminf(fmaxf(x, 1e-5f), 0.99999f);
}
__device__ __forceinline__ unsigned f2mono(float f) {
    unsigned u = __float_as_uint(f);
    return (u & 0x80000000u) ? ~u : (u | 0x80000000u);
}
__device__ __forceinline__ float mono2f(unsigned e) {
    return __uint_as_float((e & 0x80000000u) ? (e ^ 0x80000000u) : ~e);
}
__device__ __forceinline__ int cand_bin(float v) {
    int b = (int)((v - 0.99f) * 102400.0f);   // 1024 bins over [0.99, 1.0)
    return min(max(b, 0), 1023);
}
__device__ __forceinline__ float dot8(float4 a, float4 b, const float* n) {
    float d = a.x * n[0];
    d = fmaf(a.y, n[1], d); d = fmaf(a.z, n[2], d); d = fmaf(a.w, n[3], d);
    d = fmaf(b.x, n[4], d); d = fmaf(b.y, n[5], d); d = fmaf(b.z, n[6], d);
    d = fmaf(b.w, n[7], d);
    return d;
}
// Identical fma ORDER to dot8, all operands BY VALUE — no address-taken
// arrays anywhere in the hot kernels (rule #20: arrays demote to scratch).
__device__ __forceinline__ float dot8v(float4 a, float4 b, float4 n0, float4 n1) {
    float d = a.x * n0.x;
    d = fmaf(a.y, n0.y, d); d = fmaf(a.z, n0.z, d); d = fmaf(a.w, n0.w, d);
    d = fmaf(b.x, n1.x, d); d = fmaf(b.y, n1.y, d); d = fmaf(b.z, n1.z, d);
    d = fmaf(b.w, n1.w, d);
    return d;
}
__device__ __forceinline__ void near_push(float* ws, int slot, float dv, int nn) {
    int* ncnt = (int*)ws + WSO_NEARCNT;
    unsigned long long* nbuf = (unsigned long long*)ws + WSO_NEAR / 2;
    int p_ = atomicAdd(&ncnt[slot], 1);
    if (p_ < NEARCAP)
        nbuf[(size_t)slot * NEARCAP + p_] =
            (((unsigned long long)__float_as_uint(dv)) << 32) | (unsigned)nn;
}

// ---------------------------------------------------------------------------
// kA: streaming pass over the 64 MB prob matrix at HBM rate.
__global__ __launch_bounds__(256) void kA_stream(
    const float* __restrict__ prob, float* __restrict__ ws)
{
    __shared__ float wred[4];
    __shared__ int lcnt;
    const int tid   = threadIdx.x;
    const int row   = blockIdx.x >> 3;
    const int chunk = blockIdx.x & 7;
    if (tid == 0) lcnt = 0;
    __syncthreads();

    unsigned long long* cb = (unsigned long long*)ws + (size_t)blockIdx.x * CCAP;
    const float4* p4 = (const float4*)(prob + (size_t)row * NPTS + (size_t)chunk * CHUNK);

    float4 v[8];
    #pragma unroll
    for (int i = 0; i < 8; i++) v[i] = p4[i * 256 + tid];   // all loads in flight

    float lsum = 0.f;
    #pragma unroll
    for (int i = 0; i < 8; i++) {
        float c0 = clipp(v[i].x), c1 = clipp(v[i].y), c2 = clipp(v[i].z), c3 = clipp(v[i].w);
        lsum += (c0 + c1) + (c2 + c3);
        float mx = fmaxf(fmaxf(c0, c1), fmaxf(c2, c3));
        if (mx >= 0.99f) {
            int bi = chunk * CHUNK + (i * 256 + tid) * 4;
            float c4[4] = {c0, c1, c2, c3};
            #pragma unroll
            for (int j = 0; j < 4; j++) {
                if (c4[j] >= 0.99f) {
                    int p_ = atomicAdd(&lcnt, 1);
                    if (p_ < CCAP)
                        cb[p_] = (((unsigned long long)__float_as_uint(c4[j])) << 32)
                               | (unsigned)~(bi + j);
                }
            }
        }
    }
    #pragma unroll
    for (int off = 32; off; off >>= 1) lsum += __shfl_down(lsum, off);
    if ((tid & 63) == 0) wred[tid >> 6] = lsum;
    __syncthreads();
    if (tid == 0) {
        ws[WSO_PSUM + blockIdx.x] = (wred[0] + wred[1]) + (wred[2] + wred[3]);
        ((int*)ws)[WSO_CCNT + blockIdx.x] = min(lcnt, CCAP);
    }
}

// ---------------------------------------------------------------------------
// kB: per-row exact top-128/top-64 SETS + weighted moments + FUSED 64-lane
// element-parallel tournament Jacobi.
constexpr int CSLOTS = CHUNKS * CCAP;      // 1280
constexpr int GITER  = CSLOTS / 256;       // 5 (exact)
__global__ __launch_bounds__(256) void kB_select(
    const float* __restrict__ points, float* __restrict__ ws)
{
    __shared__ unsigned long long cand[CSLOTS];         // 1280 -> 10 KB
    __shared__ unsigned long long comp[256];
    __shared__ int   hist[1024];
    __shared__ int   counts_s[CHUNKS];
    __shared__ int   ccnt_s, bt_s;
    __shared__ float sw[128];
    __shared__ float pc[128][9];                        // col 8 == 1.0f
    __shared__ float sred[44][4];
    __shared__ float slotm[44];
    __shared__ float wpart[2];
    __shared__ float covm[64];

    const int row = blockIdx.x;
    const int tid = threadIdx.x;

    if (tid < CHUNKS) counts_s[tid] = ((const int*)ws)[WSO_CCNT + row * CHUNKS + tid];
    if (tid == 0) { ccnt_s = 0; bt_s = 0; }
    #pragma unroll
    for (int k = 0; k < 4; k++) hist[tid * 4 + k] = 0;
    __syncthreads();

    // fixed-stride gather + histogram over the 8 per-chunk candidate segments
    const unsigned long long* cb = (const unsigned long long*)ws;
    #pragma unroll
    for (int r = 0; r < GITER; r++) {
        int s = r * 256 + tid;
        int c = s / CCAP, t = s - c * CCAP;
        unsigned long long k = 0ull;
        if (t < counts_s[c]) {
            k = cb[(size_t)(row * CHUNKS + c) * CCAP + t];
            atomicAdd(&hist[cand_bin(__uint_as_float((unsigned)(k >> 32)))], 1);
        }
        cand[s] = k;
    }
    __syncthreads();

    // threshold bin via one wave: suffix-scan 64 groups of 16 bins
    if (tid < 64) {
        int h[16]; int g = 0;
        #pragma unroll
        for (int k = 0; k < 16; k++) { h[k] = hist[tid * 16 + k]; g += h[k]; }
        int s = g;
        #pragma unroll
        for (int off = 1; off < 64; off <<= 1) {
            int o = __shfl_down(s, off);
            if (tid + off < 64) s += o;
        }
        int Snext = __shfl_down(s, 1);
        if (tid == 63) Snext = 0;
        if (s >= 128 && Snext < 128) {   // exactly one lane
            int acc = Snext, bt = tid * 16;
            #pragma unroll
            for (int k = 15; k >= 0; k--) {
                acc += h[k];
                if (acc >= 128) { bt = tid * 16 + k; break; }
            }
            bt_s = bt;
        }
    }
    __syncthreads();

    // compact survivors (bin >= bt); m in [128, ~140]
    const int bt = bt_s;
    #pragma unroll
    for (int r = 0; r < GITER; r++) {
        unsigned long long k = cand[r * 256 + tid];
        if (k && cand_bin(__uint_as_float((unsigned)(k >> 32))) >= bt) {
            int p_ = atomicAdd(&ccnt_s, 1);
            if (p_ < 256) comp[p_] = k;
        }
    }
    __syncthreads();
    const int m = min(ccnt_s, 256);

    if (tid < 128) {
        sw[tid] = 0.f;
        #pragma unroll
        for (int j = 0; j < 9; j++) pc[tid][j] = (j == 8) ? 1.f : 0.f;
    }
    if (tid < 64) {
        ws[WSO_T64V + (size_t)row * 64 + tid] = 0.f;
        ((int*)ws)[WSO_T64I + (size_t)row * 64 + tid] = 0;
    }
    // rank of each survivor vs all m keys (broadcast LDS reads, unique keys)
    unsigned long long ki = (tid < m) ? comp[tid] : 0ull;
    int rank = 0;
    for (int j = 0; j < m; j++) rank += (comp[j] > ki) ? 1 : 0;
    __syncthreads();

    // scatter by rank: slots 0..127 = exact top-128 (rank order = lax.top_k order)
    if (tid < m && rank < 128) {
        float v = __uint_as_float((unsigned)(ki >> 32));
        unsigned idx = ~(unsigned)(ki & 0xFFFFFFFFu);
        sw[rank] = v;
        const float4* pt = (const float4*)(points + (size_t)idx * 8);
        float4 q0 = pt[0], q1 = pt[1];
        pc[rank][0] = q0.x; pc[rank][1] = q0.y; pc[rank][2] = q0.z; pc[rank][3] = q0.w;
        pc[rank][4] = q1.x; pc[rank][5] = q1.y; pc[rank][6] = q1.z; pc[rank][7] = q1.w;
        if (rank < 64) {
            ws[WSO_T64V + (size_t)row * 64 + rank] = v;
            ((int*)ws)[WSO_T64I + (size_t)row * 64 + rank] = (int)idx;
        }
    }
    __syncthreads();

    if (tid < 128) {
        float ww = sw[tid];
        #pragma unroll
        for (int off = 32; off; off >>= 1) ww += __shfl_down(ww, off);
        if ((tid & 63) == 0) wpart[tid >> 6] = ww;
    }
    // moments: 44 slots x 4 partials (tid < 176)
    if (tid < 176) {
        int s = tid >> 2, part = tid & 3;
        int i_, j_;
        if (s < 36) {
            int rem = s; i_ = 0;
            while (rem >= 8 - i_) { rem -= 8 - i_; i_++; }
            j_ = i_ + rem;
        } else { i_ = s - 36; j_ = 8; }
        float acc = 0.f;
        for (int k = part * 32; k < part * 32 + 32; k++)
            acc += sw[k] * pc[k][i_] * pc[k][j_];
        sred[s][part] = acc;
    }
    __syncthreads();
    if (tid < 44) slotm[tid] = (sred[tid][0] + sred[tid][1]) + (sred[tid][2] + sred[tid][3]);
    __syncthreads();

    if (tid < 64) {
        float w128 = fmaxf(wpart[0] + wpart[1], 1e-6f);
        int i_ = tid >> 3, j_ = tid & 7;
        int a_ = min(i_, j_), b_ = max(i_, j_);
        int s3 = 8 * a_ - (a_ * (a_ - 1)) / 2 + (b_ - a_);
        covm[tid] = slotm[s3] / w128 - (slotm[36 + i_] / w128) * (slotm[36 + j_] / w128);
    }
    __syncthreads();

    // housekeeping on wave 1 (wave 0 starts the eigensolve immediately)
    if (tid == 64) {
        ws[WSO_ANORM + row] = fmaxf(wpart[0], 1e-6f);
        float s = 0.f;
        for (int c = 0; c < CHUNKS; c++) s += ws[WSO_PSUM + row * CHUNKS + c];
        ws[WSO_SUMP + row] = s;
        ((unsigned*)ws)[WSO_PMAXP + row] = 0u;          // init for k3a atomicMax
        ((unsigned*)ws)[WSO_PMAXN + row] = 0u;
        ((int*)ws)[WSO_NEARCNT + row * 2 + 0] = 0;      // init near-max lists
        ((int*)ws)[WSO_NEARCNT + row * 2 + 1] = 0;
    }

    // ---- fused element-parallel Jacobi (wave 0; lane = i*8+j owns A[i][j]) ----
    if (tid < 64) {
        const int i = tid >> 3, j = tid & 7;
        float a = covm[tid];
        float v = (i == j) ? 1.f : 0.f;
        // round-robin tournament pairings; octal digit i = partner(i)
        const unsigned PR[7] = {023456701u, 001234567u, 050712346u, 034067125u,
                                012305674u, 067120453u, 045671032u};
        #pragma unroll 1
        for (int sweep = 0; sweep < 6; sweep++) {
            #pragma unroll
            for (int r = 0; r < 7; r++) {
                const unsigned pk = PR[r];
                const int rp = (pk >> (3 * i)) & 7;       // row-pair partner
                const int cp = (pk >> (3 * j)) & 7;       // col-pair partner
                const int pr = min(i, rp), qr = max(i, rp);
                float app = __shfl(a, pr * 9);
                float aqq = __shfl(a, qr * 9);
                float apq = __shfl(a, pr * 8 + qr);
                float tau = 0.5f * (aqq - app);
                float den = fabsf(tau) + sqrtf(fmaf(tau, tau, apq * apq));
                float t = __fdividef(apq, den + 1e-38f);  // apq==0 -> identity
                t = (tau < 0.f) ? -t : t;
                float cr = rsqrtf(fmaf(t, t, 1.f));
                float sr = t * cr;
                float cc = __shfl(cr, j * 9);
                float sc = __shfl(sr, j * 9);
                float oth = __shfl(a, rp * 8 + j);        // row phase (J^T A)
                a = fmaf((i < rp) ? -sr : sr, oth, cr * a);
                float oth2 = __shfl(a, i * 8 + cp);       // col phase (A J)
                a = fmaf((j < cp) ? -sc : sc, oth2, cc * a);
                float ov = __shfl(v, i * 8 + cp);
                v = fmaf((j < cp) ? -sc : sc, ov, cc * v);
            }
        }
        float d[8];
        #pragma unroll
        for (int k = 0; k < 8; k++) d[k] = __shfl(a, k * 9);
        float e0 = d[0]; int i0 = 0;
        #pragma unroll
        for (int k = 1; k < 8; k++) if (d[k] < e0) { e0 = d[k]; i0 = k; }
        float e1 = 3.4e38f;
        #pragma unroll
        for (int k = 0; k < 8; k++) if (k != i0 && d[k] < e1) e1 = d[k];
        if (tid == 0) {
            ws[WSO_PLANE + row] = e0;
            ws[WSO_FACET + row] = e0 / (e1 + 1e-6f);
        }
        if (j == i0) ws[WSO_NRM + (size_t)row * 8 + i] = v;   // V[:,i0]
        // eigenvector sign arbitrary: boundary = min(b_pos, b_neg) is sign-invariant
    }
}

// ---------------------------------------------------------------------------
// k3a: 4 rows/block x 2048 points/block, TWO passes. ALL state in NAMED
// scalars/float4s — the R1/R2/R3 versions kept nr[4][8]/q[4][2] arrays that
// the compiler demoted to scratch (VGPR_Count 28-40 vs >=72 live = proof),
// costing a ~268-537 MB scratch round-trip = the whole 41-82 us. Points are
// L2-resident (2 MB); 268 MB of L2 reads ~8 us.
constexpr int R3 = 4;
constexpr int P3 = 2048;
__global__ __launch_bounds__(256) void k3a_max(
    const float* __restrict__ points, float* __restrict__ ws)
{
    __shared__ float red[4][8];
    __shared__ float bmaxs[8];
    const int tid = threadIdx.x;
    const int r0  = blockIdx.y * R3;
    const float4* nv = (const float4*)(ws + WSO_NRM);
    const float4 na0 = nv[(r0 + 0) * 2], na1 = nv[(r0 + 0) * 2 + 1];
    const float4 nb0 = nv[(r0 + 1) * 2], nb1 = nv[(r0 + 1) * 2 + 1];
    const float4 nc0 = nv[(r0 + 2) * 2], nc1 = nv[(r0 + 2) * 2 + 1];
    const float4 nd0 = nv[(r0 + 3) * 2], nd1 = nv[(r0 + 3) * 2 + 1];
    float mpa = -3.4e38f, mna = -3.4e38f, mpb = -3.4e38f, mnb = -3.4e38f;
    float mpc = -3.4e38f, mnc = -3.4e38f, mpd = -3.4e38f, mnd = -3.4e38f;
    const float4* pb = (const float4*)points + (size_t)blockIdx.x * (P3 * 2);

    #pragma unroll
    for (int it = 0; it < P3 / 256; it++) {
        int t2 = (it * 256 + tid) * 2;
        float4 q0 = pb[t2], q1 = pb[t2 + 1];
        float da = dot8v(q0, q1, na0, na1);
        float db = dot8v(q0, q1, nb0, nb1);
        float dc = dot8v(q0, q1, nc0, nc1);
        float dd = dot8v(q0, q1, nd0, nd1);
        mpa = fmaxf(mpa, da); mna = fmaxf(mna, -da);
        mpb = fmaxf(mpb, db); mnb = fmaxf(mnb, -db);
        mpc = fmaxf(mpc, dc); mnc = fmaxf(mnc, -dc);
        mpd = fmaxf(mpd, dd); mnd = fmaxf(mnd, -dd);
    }
    #pragma unroll
    for (int off = 32; off; off >>= 1) {
        mpa = fmaxf(mpa, __shfl_xor(mpa, off)); mna = fmaxf(mna, __shfl_xor(mna, off));
        mpb = fmaxf(mpb, __shfl_xor(mpb, off)); mnb = fmaxf(mnb, __shfl_xor(mnb, off));
        mpc = fmaxf(mpc, __shfl_xor(mpc, off)); mnc = fmaxf(mnc, __shfl_xor(mnc, off));
        mpd = fmaxf(mpd, __shfl_xor(mpd, off)); mnd = fmaxf(mnd, __shfl_xor(mnd, off));
    }
    if ((tid & 63) == 0) {
        int wv = tid >> 6;
        red[wv][0] = mpa; red[wv][1] = mna; red[wv][2] = mpb; red[wv][3] = mnb;
        red[wv][4] = mpc; red[wv][5] = mnc; red[wv][6] = mpd; red[wv][7] = mnd;
    }
    __syncthreads();
    if (tid < 8) {
        float m = fmaxf(fmaxf(red[0][tid], red[1][tid]), fmaxf(red[2][tid], red[3][tid]));
        bmaxs[tid] = m;
        int r = r0 + (tid >> 1);
        unsigned* wsu = (unsigned*)ws;
        atomicMax(&wsu[((tid & 1) ? WSO_PMAXN : WSO_PMAXP) + r], f2mono(m));
    }
    __syncthreads();
    const float bpa = bmaxs[0] - 0.05f, bna = bmaxs[1] - 0.05f;
    const float bpb = bmaxs[2] - 0.05f, bnb = bmaxs[3] - 0.05f;
    const float bpc = bmaxs[4] - 0.05f, bnc = bmaxs[5] - 0.05f;
    const float bpd = bmaxs[6] - 0.05f, bnd = bmaxs[7] - 0.05f;

    // pass 2: reload (L1/L2-hot) + recompute + filter vs block max (superset
    // of the global-max filter; k3cd re-checks vs global max). Opaque pointer
    // stops CSE from keeping 32 pass-1 d values live (the R1 dsv disaster).
    const float4* pb2 = pb;
    asm volatile("" : "+v"(pb2));
    #pragma unroll 4
    for (int it = 0; it < P3 / 256; it++) {
        int t2 = (it * 256 + tid) * 2;
        float4 q0 = pb2[t2], q1 = pb2[t2 + 1];
        int nn = blockIdx.x * P3 + it * 256 + tid;
        float da = dot8v(q0, q1, na0, na1);
        float db = dot8v(q0, q1, nb0, nb1);
        float dc = dot8v(q0, q1, nc0, nc1);
        float dd = dot8v(q0, q1, nd0, nd1);
        if (da >= bpa)  near_push(ws, (r0 + 0) * 2 + 0,  da, nn);
        if (-da >= bna) near_push(ws, (r0 + 0) * 2 + 1, -da, nn);
        if (db >= bpb)  near_push(ws, (r0 + 1) * 2 + 0,  db, nn);
        if (-db >= bnb) near_push(ws, (r0 + 1) * 2 + 1, -db, nn);
        if (dc >= bpc)  near_push(ws, (r0 + 2) * 2 + 0,  dc, nn);
        if (-dc >= bnc) near_push(ws, (r0 + 2) * 2 + 1, -dc, nn);
        if (dd >= bpd)  near_push(ws, (r0 + 3) * 2 + 0,  dd, nn);
        if (-dd >= bnd) near_push(ws, (r0 + 3) * 2 + 1, -dd, nn);
    }
}

// ---------------------------------------------------------------------------
// k3cd: fused inactive term (near-max lists) + active term (top-64) + combine.
__global__ __launch_bounds__(64) void k3cd_final(
    const float* __restrict__ points, const float* __restrict__ prob,
    const float* __restrict__ ws, float* __restrict__ out)
{
    const int row = blockIdx.x;
    const int t   = threadIdx.x;
    const unsigned* wsu = (const unsigned*)ws;
    __shared__ float nl[8];
    if (t < 8) nl[t] = ws[WSO_NRM + (size_t)row * 8 + t];
    __syncthreads();

    const float pmaxp = mono2f(wsu[WSO_PMAXP + row]);
    const float pmaxn = mono2f(wsu[WSO_PMAXN + row]);

    // active term over top-64
    float w   = ws[WSO_T64V + (size_t)row * 64 + t];
    int   idx = ((const int*)ws)[WSO_T64I + (size_t)row * 64 + t];
    const float4* pt = (const float4*)(points + (size_t)idx * 8);
    float4 q0 = pt[0], q1 = pt[1];
    float d = dot8(q0, q1, nl);
    float sp = d - pmaxp, sn = -d - pmaxn;
    float ap = w * sp * sp;
    float an = w * sn * sn;

    // inactive term from near-max lists
    const int* ncnt = (const int*)ws + WSO_NEARCNT;
    const unsigned long long* nbuf = (const unsigned long long*)ws + WSO_NEAR / 2;
    float ip = 0.f, in_ = 0.f;
    int cp = min(ncnt[row * 2 + 0], NEARCAP);
    int cn = min(ncnt[row * 2 + 1], NEARCAP);
    for (int i = t; i < cp; i += 64) {
        unsigned long long e = nbuf[(size_t)(row * 2 + 0) * NEARCAP + i];
        float dv = __uint_as_float((unsigned)(e >> 32));
        float tp = 0.05f + (dv - pmaxp);
        if (tp > 0.f) {
            float w2 = 1.0f - clipp(prob[(size_t)row * NPTS + (unsigned)(e & 0xFFFFFFFFu)]);
            ip = fmaf(w2 * tp, tp, ip);
        }
    }
    for (int i = t; i < cn; i += 64) {
        unsigned long long e = nbuf[(size_t)(row * 2 + 1) * NEARCAP + i];
        float dv = __uint_as_float((unsigned)(e >> 32));
        float tn = 0.05f + (dv - pmaxn);
        if (tn > 0.f) {
            float w2 = 1.0f - clipp(prob[(size_t)row * NPTS + (unsigned)(e & 0xFFFFFFFFu)]);
            in_ = fmaf(w2 * tn, tn, in_);
        }
    }
    #pragma unroll
    for (int off = 32; off; off >>= 1) {
        ap  += __shfl_down(ap, off);
        an  += __shfl_down(an, off);
        ip  += __shfl_down(ip, off);
        in_ += __shfl_down(in_, off);
    }
    if (t == 0) {
        float anorm = ws[WSO_ANORM + row];
        float sump  = ws[WSO_SUMP + row];
        float inorm = fmaxf((float)NPTS - sump, 1e-6f);
        float bp = (ap / anorm) + 0.35f * (ip / inorm);
        float bn = (an / anorm) + 0.35f * (in_ / inorm);
        float bd = (bp <= bn) ? bp : bn;
        float def = fmaxf(26.0f - sump, 0.f);
        out[row] = ws[WSO_PLANE + row] + 8.0f * ws[WSO_FACET + row]
                 + 4.0f * bd + 25.0f * def * def;
    }
}

// ---------------------------------------------------------------------------
extern "C" void kernel_launch(void* const* d_in, const int* in_sizes, int n_in,
                              void* d_out, int out_size, void* d_ws, size_t ws_size,
                              hipStream_t stream) {
    const float* prob   = (const float*)d_in[0];  // (256, 65536) f32
    const float* points = (const float*)d_in[1];  // (65536, 8) f32
    float* out = (float*)d_out;                   // (256,) f32
    float* ws  = (float*)d_ws;                    // 3.66 MiB used

    kA_stream<<<NBLK, 256, 0, stream>>>(prob, ws);
    kB_select<<<B, 256, 0, stream>>>(points, ws);
    dim3 g3(NPTS / P3, B / R3);                   // (32, 64)
    k3a_max<<<g3, 256, 0, stream>>>(points, ws);
    k3cd_final<<<B, 64, 0, stream>>>(points, prob, ws, out);
}